// Round 3
// baseline (194.044 us; speedup 1.0000x reference)
//
#include <hip/hip_runtime.h>
#include <hip/hip_bf16.h>

#define BF16 __hip_bfloat16

typedef __attribute__((ext_vector_type(8))) short bf16x8;
typedef __attribute__((ext_vector_type(4))) float f32x4;
typedef __attribute__((ext_vector_type(4))) unsigned short ushort4v;
typedef __attribute__((ext_vector_type(4))) float float4v;

__device__ __forceinline__ unsigned short f2bf(float f) {
  BF16 h = __float2bfloat16(f);
  union { BF16 h; unsigned short u; } cv;
  cv.h = h;
  return cv.u;
}

// ---------------------------------------------------------------------------
// Kernel 1: cast weights fp32 -> bf16
// ---------------------------------------------------------------------------
__global__ __launch_bounds__(256) void cast_w_kernel(const float* __restrict__ qw,
                                                     const float* __restrict__ pw,
                                                     BF16* __restrict__ wq,
                                                     BF16* __restrict__ wp) {
  int i = blockIdx.x * 256 + threadIdx.x;
  if (i < 1536 * 512) wq[i] = __float2bfloat16(qw[i]);
  if (i < 512 * 512)  wp[i] = __float2bfloat16(pw[i]);
}

// ---------------------------------------------------------------------------
// Kernel 2: GroupNorm. One block per (batch, group). Writes h transposed:
// h_t[b][n][c] bf16 (so GEMM B-operand has K=c contiguous per pixel n).
// ---------------------------------------------------------------------------
__global__ __launch_bounds__(256) void gn_kernel(const float* __restrict__ x,
                                                 const float* __restrict__ gw,
                                                 const float* __restrict__ gb,
                                                 BF16* __restrict__ h_t) {
  const int blk = blockIdx.x;          // 0..255
  const int bb = blk >> 5, g = blk & 31;
  const float* xg = x + (size_t)(bb * 512 + g * 16) * 1024;  // 16 ch x 1024 px

  float s = 0.f, ss = 0.f;
  const float4v* x4 = (const float4v*)xg;
  for (int i = threadIdx.x; i < 4096; i += 256) {   // 16384 floats / 4
    float4v v = x4[i];
    s  += v[0] + v[1] + v[2] + v[3];
    ss += v[0] * v[0] + v[1] * v[1] + v[2] * v[2] + v[3] * v[3];
  }
  // wave reduce (width 64)
  for (int off = 32; off > 0; off >>= 1) {
    s  += __shfl_down(s, off, 64);
    ss += __shfl_down(ss, off, 64);
  }
  __shared__ float sred[8];
  const int wv = threadIdx.x >> 6;
  if ((threadIdx.x & 63) == 0) { sred[wv] = s; sred[4 + wv] = ss; }
  __syncthreads();
  const float S  = sred[0] + sred[1] + sred[2] + sred[3];
  const float SS = sred[4] + sred[5] + sred[6] + sred[7];
  const float mean = S * (1.f / 16384.f);
  const float var  = SS * (1.f / 16384.f) - mean * mean;
  const float rstd = rsqrtf(var + 1e-5f);

  const int ci = threadIdx.x & 15, nb = threadIdx.x >> 4;
  const int c  = g * 16 + ci;
  const float aw = gw[c] * rstd;
  const float ab = gb[c] - mean * aw;
  const float* xrow = xg + (size_t)ci * 1024;
  BF16* hb = h_t + (size_t)bb * 1024 * 512 + c;
  #pragma unroll 4
  for (int i = 0; i < 64; ++i) {
    int n = nb + i * 16;
    hb[(size_t)n * 512] = __float2bfloat16(aw * xrow[n] + ab);
  }
}

// ---------------------------------------------------------------------------
// GEMM core helpers. Tile 128x128, BK=64, 4 waves (each 64x64), bf16 MFMA.
// LDS tiles stored [row][64] with 16B-chunk XOR swizzle: cS = cG ^ (row&7)
// -> conflict-free ds_read_b128 of K-contiguous fragments.
// ---------------------------------------------------------------------------
#define GEMM_PROLOGUE()                                                        \
  const int tid = threadIdx.x, l = tid & 63, wv = tid >> 6;                    \
  const int wm = wv >> 1, wn = wv & 1;                                         \
  const int lc = l & 15, lh = l >> 4;                                          \
  __shared__ BF16 Al[128 * 64];                                                \
  __shared__ BF16 Bl[128 * 64];                                                \
  f32x4 acc[4][4] = {};                                                        \
  for (int kt = 0; kt < 8; ++kt) {                                             \
    const int k0 = kt * 64;                                                    \
    __syncthreads();                                                           \
    _Pragma("unroll")                                                          \
    for (int it = 0; it < 4; ++it) {                                           \
      int sidx = it * 256 + tid;                                               \
      int row = sidx >> 3, cG = sidx & 7, cS = cG ^ (row & 7);                 \
      *(bf16x8*)&Al[(row * 8 + cS) * 8] =                                      \
          *(const bf16x8*)&A[(size_t)row * 512 + k0 + cG * 8];                 \
      *(bf16x8*)&Bl[(row * 8 + cS) * 8] =                                      \
          *(const bf16x8*)&B[(size_t)row * 512 + k0 + cG * 8];                 \
    }                                                                          \
    __syncthreads();                                                           \
    _Pragma("unroll")                                                          \
    for (int ks = 0; ks < 2; ++ks) {                                           \
      bf16x8 af[4], bfr[4];                                                    \
      _Pragma("unroll")                                                        \
      for (int i = 0; i < 4; ++i) {                                            \
        int rA = wm * 64 + i * 16 + lc;                                        \
        int cA = (ks * 4 + lh) ^ (rA & 7);                                     \
        af[i] = *(const bf16x8*)&Al[(rA * 8 + cA) * 8];                        \
        int rB = wn * 64 + i * 16 + lc;                                        \
        int cB = (ks * 4 + lh) ^ (rB & 7);                                     \
        bfr[i] = *(const bf16x8*)&Bl[(rB * 8 + cB) * 8];                       \
      }                                                                        \
      _Pragma("unroll")                                                        \
      for (int i = 0; i < 4; ++i)                                              \
        _Pragma("unroll")                                                      \
        for (int j = 0; j < 4; ++j)                                            \
          acc[i][j] = __builtin_amdgcn_mfma_f32_16x16x32_bf16(af[i], bfr[j],   \
                                                              acc[i][j], 0, 0, 0); \
    }                                                                          \
  }

// QKV GEMM: A = qkv_w bf16 [1536][512]; B = h_t[b] [1024][512] ([n][c]).
// mt 0..3 -> Q (store transposed [bh][n][d], scaled by 1/8),
// mt 4..7 -> K (transposed), mt 8..11 -> V (natural [bh][d][n]).
__global__ __launch_bounds__(256) void qkv_gemm_kernel(const BF16* __restrict__ Wq,
                                                       const BF16* __restrict__ Ht,
                                                       const float* __restrict__ bias,
                                                       BF16* __restrict__ q_t,
                                                       BF16* __restrict__ k_t,
                                                       BF16* __restrict__ v_nat) {
  const int nt = blockIdx.x, mt = blockIdx.y, b = blockIdx.z;
  const int m0 = mt * 128, n0 = nt * 128;
  const BF16* A = Wq + (size_t)m0 * 512;
  const BF16* B = Ht + (size_t)b * 1024 * 512 + (size_t)n0 * 512;
  GEMM_PROLOGUE()

  const int r0 = lh * 4;
  #pragma unroll
  for (int mi = 0; mi < 4; ++mi) {
    const int o = m0 + wm * 64 + mi * 16 + r0;   // output row (o..o+3)
    #pragma unroll
    for (int ni = 0; ni < 4; ++ni) {
      const int pix = n0 + wn * 64 + ni * 16 + lc;
      f32x4 a = acc[mi][ni];
      if (mt < 8) {  // q or k: transposed store [bh][pix][d], 4 contiguous d
        const float scale = (mt < 4) ? 0.125f : 1.0f;
        const int hh = (o >> 6) & 7;
        const int d = o & 63;
        BF16* dst = (mt < 4 ? q_t : k_t) +
                    ((size_t)(b * 8 + hh) * 1024 + pix) * 64 + d;
        ushort4v pk;
        #pragma unroll
        for (int r = 0; r < 4; ++r) pk[r] = f2bf((a[r] + bias[o + r]) * scale);
        *(ushort4v*)dst = pk;
      } else {       // v: natural [b*512 + vr][pix]
        #pragma unroll
        for (int r = 0; r < 4; ++r) {
          const int vr = o + r - 1024;
          v_nat[((size_t)(b * 512 + vr)) * 1024 + pix] =
              __float2bfloat16(a[r] + bias[o + r]);
        }
      }
    }
  }
}

// Proj GEMM + bias + residual: A = proj_w bf16 [512][512]; B = attout[b]
// [1024][512] ([n][c]); out fp32 [b][c][n] = x + bias + acc.
__global__ __launch_bounds__(256) void proj_gemm_kernel(const BF16* __restrict__ Wp,
                                                        const BF16* __restrict__ At,
                                                        const float* __restrict__ bias,
                                                        const float* __restrict__ x,
                                                        float* __restrict__ out) {
  const int nt = blockIdx.x, mt = blockIdx.y, b = blockIdx.z;
  const int m0 = mt * 128, n0 = nt * 128;
  const BF16* A = Wp + (size_t)m0 * 512;
  const BF16* B = At + (size_t)b * 1024 * 512 + (size_t)n0 * 512;
  GEMM_PROLOGUE()

  const int r0 = lh * 4;
  #pragma unroll
  for (int mi = 0; mi < 4; ++mi) {
    #pragma unroll
    for (int ni = 0; ni < 4; ++ni) {
      const int n = n0 + wn * 64 + ni * 16 + lc;
      f32x4 a = acc[mi][ni];
      #pragma unroll
      for (int r = 0; r < 4; ++r) {
        const int c = m0 + wm * 64 + mi * 16 + r0 + r;
        const size_t idx = ((size_t)(b * 512 + c)) * 1024 + n;
        out[idx] = x[idx] + bias[c] + a[r];
      }
    }
  }
}

// ---------------------------------------------------------------------------
// Kernel 4: flash attention. Block = (q-tile of 64 rows, bh). 4 waves, each
// owns 16 q-rows. K-tiles of 64 cols, online softmax in registers.
// Q/K stored [bh][n][d] (K-contiguous for both A and B fragments of QK^T),
// V stored [bh][d][n] (K=j contiguous for the PV B fragment).
// ---------------------------------------------------------------------------
__global__ __launch_bounds__(256) void attn_kernel(const BF16* __restrict__ q_t,
                                                   const BF16* __restrict__ k_t,
                                                   const BF16* __restrict__ v_nat,
                                                   BF16* __restrict__ attout) {
  const int bh = blockIdx.y;  // b*8 + h
  const int b = bh >> 3, hh = bh & 7;
  const int i0 = blockIdx.x * 64;
  const int tid = threadIdx.x, l = tid & 63, wv = tid >> 6;
  const int lc = l & 15, lh = l >> 4;

  __shared__ __align__(16) BF16 Kl[64 * 64];      // [j][d] swizzled
  __shared__ __align__(16) BF16 Vl[64 * 64];      // [d][j] swizzled
  __shared__ __align__(16) BF16 Pl[4][16][72];    // per-wave P, padded rows

  // Q fragments (row = lc within wave's 16 rows), held for whole loop
  bf16x8 aq0, aq1;
  {
    const BF16* qp = q_t + ((size_t)bh * 1024 + i0 + wv * 16 + lc) * 64;
    aq0 = *(const bf16x8*)&qp[lh * 8];
    aq1 = *(const bf16x8*)&qp[32 + lh * 8];
  }

  f32x4 O[4] = {};
  float mrow[4], lrow[4];
  #pragma unroll
  for (int r = 0; r < 4; ++r) { mrow[r] = -1e30f; lrow[r] = 0.f; }

  const BF16* kbase = k_t + (size_t)bh * 1024 * 64;
  const BF16* vbase = v_nat + (size_t)bh * 64 * 1024;

  for (int jt = 0; jt < 16; ++jt) {
    const int j0 = jt * 64;
    __syncthreads();   // protect K/V LDS from previous iteration's readers
    #pragma unroll
    for (int it = 0; it < 2; ++it) {
      int sidx = it * 256 + tid;
      int row = sidx >> 3, cG = sidx & 7, cS = cG ^ (row & 7);
      *(bf16x8*)&Kl[(row * 8 + cS) * 8] =
          *(const bf16x8*)&kbase[((size_t)(j0 + row)) * 64 + cG * 8];
      *(bf16x8*)&Vl[(row * 8 + cS) * 8] =
          *(const bf16x8*)&vbase[(size_t)row * 1024 + j0 + cG * 8];
    }
    __syncthreads();

    // S = Q K^T (16 q-rows x 64 j)
    f32x4 Sv[4];
    #pragma unroll
    for (int jf = 0; jf < 4; ++jf) {
      f32x4 sacc = {};
      const int jl = jf * 16 + lc;
      {
        int cS = lh ^ (jl & 7);
        bf16x8 bk = *(const bf16x8*)&Kl[(jl * 8 + cS) * 8];
        sacc = __builtin_amdgcn_mfma_f32_16x16x32_bf16(aq0, bk, sacc, 0, 0, 0);
        cS = (4 + lh) ^ (jl & 7);
        bk = *(const bf16x8*)&Kl[(jl * 8 + cS) * 8];
        sacc = __builtin_amdgcn_mfma_f32_16x16x32_bf16(aq1, bk, sacc, 0, 0, 0);
      }
      Sv[jf] = sacc;
    }

    // online softmax update (rows r: q-row = 4*lh + r, cols across lc lanes)
    float pr[4][4];
    #pragma unroll
    for (int r = 0; r < 4; ++r) {
      float tmax = fmaxf(fmaxf(Sv[0][r], Sv[1][r]), fmaxf(Sv[2][r], Sv[3][r]));
      tmax = fmaxf(tmax, __shfl_xor(tmax, 1, 64));
      tmax = fmaxf(tmax, __shfl_xor(tmax, 2, 64));
      tmax = fmaxf(tmax, __shfl_xor(tmax, 4, 64));
      tmax = fmaxf(tmax, __shfl_xor(tmax, 8, 64));
      const float mnew = fmaxf(mrow[r], tmax);
      const float sc = __expf(mrow[r] - mnew);
      mrow[r] = mnew;
      float rs = 0.f;
      #pragma unroll
      for (int jf = 0; jf < 4; ++jf) {
        float p = __expf(Sv[jf][r] - mnew);
        pr[jf][r] = p;
        rs += p;
      }
      rs += __shfl_xor(rs, 1, 64);
      rs += __shfl_xor(rs, 2, 64);
      rs += __shfl_xor(rs, 4, 64);
      rs += __shfl_xor(rs, 8, 64);
      lrow[r] = lrow[r] * sc + rs;
      #pragma unroll
      for (int nf = 0; nf < 4; ++nf) O[nf][r] *= sc;
    }

    // stage P (wave-private LDS, D-layout -> A-layout transpose)
    #pragma unroll
    for (int jf = 0; jf < 4; ++jf)
      #pragma unroll
      for (int r = 0; r < 4; ++r)
        Pl[wv][4 * lh + r][jf * 16 + lc] = __float2bfloat16(pr[jf][r]);

    // PV: O += P @ V^T   (A = P [16 x 64j], B = V^T from Vl [d][j])
    const bf16x8 ap0 = *(const bf16x8*)&Pl[wv][lc][lh * 8];
    const bf16x8 ap1 = *(const bf16x8*)&Pl[wv][lc][32 + lh * 8];
    #pragma unroll
    for (int nf = 0; nf < 4; ++nf) {
      const int dl = nf * 16 + lc;
      int cS = lh ^ (dl & 7);
      bf16x8 bv = *(const bf16x8*)&Vl[(dl * 8 + cS) * 8];
      O[nf] = __builtin_amdgcn_mfma_f32_16x16x32_bf16(ap0, bv, O[nf], 0, 0, 0);
      cS = (4 + lh) ^ (dl & 7);
      bv = *(const bf16x8*)&Vl[(dl * 8 + cS) * 8];
      O[nf] = __builtin_amdgcn_mfma_f32_16x16x32_bf16(ap1, bv, O[nf], 0, 0, 0);
    }
  }

  // epilogue: attout[b][i][hh*64 + d] bf16
  #pragma unroll
  for (int r = 0; r < 4; ++r) {
    const float inv = 1.0f / lrow[r];
    const int irow = i0 + wv * 16 + 4 * lh + r;
    BF16* dst = attout + ((size_t)b * 1024 + irow) * 512 + hh * 64;
    #pragma unroll
    for (int nf = 0; nf < 4; ++nf)
      dst[nf * 16 + lc] = __float2bfloat16(O[nf][r] * inv);
  }
}

// ---------------------------------------------------------------------------
extern "C" void kernel_launch(void* const* d_in, const int* in_sizes, int n_in,
                              void* d_out, int out_size, void* d_ws, size_t ws_size,
                              hipStream_t stream) {
  const float* x      = (const float*)d_in[0];
  const float* gn_w   = (const float*)d_in[1];
  const float* gn_b   = (const float*)d_in[2];
  const float* qkv_w  = (const float*)d_in[3];
  const float* qkv_b  = (const float*)d_in[4];
  const float* proj_w = (const float*)d_in[5];
  const float* proj_b = (const float*)d_in[6];
  float* out = (float*)d_out;

  char* ws = (char*)d_ws;
  BF16* wq    = (BF16*)(ws);                     // 1536*512*2 = 1.5 MB
  BF16* wp    = (BF16*)(ws + 1572864);           // 512*512*2  = 0.5 MB
  BF16* h_t   = (BF16*)(ws + 2097152);           // 8*1024*512*2 = 8 MB
  BF16* q_t   = (BF16*)(ws + 10485760);          // 8 MB
  BF16* k_t   = (BF16*)(ws + 18874368);          // 8 MB
  BF16* v_nat = (BF16*)(ws + 27262976);          // 8 MB; end = 35651584
  BF16* attout = h_t;  // h_t dead after qkv GEMM; reuse for attention output

  cast_w_kernel<<<3072, 256, 0, stream>>>(qkv_w, proj_w, wq, wp);
  gn_kernel<<<256, 256, 0, stream>>>(x, gn_w, gn_b, h_t);
  qkv_gemm_kernel<<<dim3(8, 12, 8), 256, 0, stream>>>(wq, h_t, qkv_b, q_t, k_t, v_nat);
  attn_kernel<<<dim3(16, 64), 256, 0, stream>>>(q_t, k_t, v_nat, attout);
  proj_gemm_kernel<<<dim3(8, 4, 8), 256, 0, stream>>>(wp, attout, proj_b, x, out);
}

// Round 4
// 184.230 us; speedup vs baseline: 1.0533x; 1.0533x over previous
//
#include <hip/hip_runtime.h>
#include <hip/hip_bf16.h>

#define BF16 __hip_bfloat16

typedef __attribute__((ext_vector_type(8))) short bf16x8;
typedef __attribute__((ext_vector_type(4))) float f32x4;
typedef __attribute__((ext_vector_type(4))) unsigned short ushort4v;
typedef __attribute__((ext_vector_type(4))) float float4v;

__device__ __forceinline__ unsigned short f2bf(float f) {
  BF16 h = __float2bfloat16(f);
  union { BF16 h; unsigned short u; } cv;
  cv.h = h;
  return cv.u;
}

// Direct global->LDS async copy, 16B per lane. LDS dest is wave-uniform base
// + lane*16 (HW rule); swizzling is done on the GLOBAL source address.
__device__ __forceinline__ void gload_lds16(const BF16* g, BF16* s) {
  __builtin_amdgcn_global_load_lds(
      (const __attribute__((address_space(1))) void*)g,
      (__attribute__((address_space(3))) void*)s, 16, 0, 0);
}

// ---------------------------------------------------------------------------
// Kernel 1: cast weights fp32 -> bf16
// ---------------------------------------------------------------------------
__global__ __launch_bounds__(256) void cast_w_kernel(const float* __restrict__ qw,
                                                     const float* __restrict__ pw,
                                                     BF16* __restrict__ wq,
                                                     BF16* __restrict__ wp) {
  int i = blockIdx.x * 256 + threadIdx.x;
  if (i < 1536 * 512) wq[i] = __float2bfloat16(qw[i]);
  if (i < 512 * 512)  wp[i] = __float2bfloat16(pw[i]);
}

// ---------------------------------------------------------------------------
// Kernel 2: GroupNorm. One block per (batch, group). Writes h transposed:
// h_t[b][n][c] bf16 (so GEMM B-operand has K=c contiguous per pixel n).
// ---------------------------------------------------------------------------
__global__ __launch_bounds__(256) void gn_kernel(const float* __restrict__ x,
                                                 const float* __restrict__ gw,
                                                 const float* __restrict__ gb,
                                                 BF16* __restrict__ h_t) {
  const int blk = blockIdx.x;          // 0..255
  const int bb = blk >> 5, g = blk & 31;
  const float* xg = x + (size_t)(bb * 512 + g * 16) * 1024;  // 16 ch x 1024 px

  float s = 0.f, ss = 0.f;
  const float4v* x4 = (const float4v*)xg;
  for (int i = threadIdx.x; i < 4096; i += 256) {   // 16384 floats / 4
    float4v v = x4[i];
    s  += v[0] + v[1] + v[2] + v[3];
    ss += v[0] * v[0] + v[1] * v[1] + v[2] * v[2] + v[3] * v[3];
  }
  for (int off = 32; off > 0; off >>= 1) {
    s  += __shfl_down(s, off, 64);
    ss += __shfl_down(ss, off, 64);
  }
  __shared__ float sred[8];
  const int wv = threadIdx.x >> 6;
  if ((threadIdx.x & 63) == 0) { sred[wv] = s; sred[4 + wv] = ss; }
  __syncthreads();
  const float S  = sred[0] + sred[1] + sred[2] + sred[3];
  const float SS = sred[4] + sred[5] + sred[6] + sred[7];
  const float mean = S * (1.f / 16384.f);
  const float var  = SS * (1.f / 16384.f) - mean * mean;
  const float rstd = rsqrtf(var + 1e-5f);

  const int ci = threadIdx.x & 15, nb = threadIdx.x >> 4;
  const int c  = g * 16 + ci;
  const float aw = gw[c] * rstd;
  const float ab = gb[c] - mean * aw;
  const float* xrow = xg + (size_t)ci * 1024;
  BF16* hb = h_t + (size_t)bb * 1024 * 512 + c;
  #pragma unroll 4
  for (int i = 0; i < 64; ++i) {
    int n = nb + i * 16;
    hb[(size_t)n * 512] = __float2bfloat16(aw * xrow[n] + ab);
  }
}

// ---------------------------------------------------------------------------
// GEMM core. Tile 128x128, BK=64, 4 waves (each 64x64), bf16 MFMA.
// Staging via global_load_lds (16B/lane, direct to LDS). LDS layout is the
// 16B-chunk XOR swizzle (slot = chunk ^ (row&7)); since the LDS dest must be
// linear in lane id, the INVERSE swizzle is applied to the global source
// address per lane (m173 pattern). Compute-side reads are conflict-free
// ds_read_b128.
// ---------------------------------------------------------------------------
#define GEMM_PROLOGUE()                                                        \
  const int tid = threadIdx.x, l = tid & 63, wv = tid >> 6;                    \
  const int wm = wv >> 1, wn = wv & 1;                                         \
  const int lc = l & 15, lh = l >> 4;                                          \
  __shared__ __align__(16) BF16 Al[128 * 64];                                  \
  __shared__ __align__(16) BF16 Bl[128 * 64];                                  \
  f32x4 acc[4][4] = {};                                                        \
  int srow[4], scg[4];                                                         \
  _Pragma("unroll")                                                            \
  for (int t = 0; t < 4; ++t) {                                                \
    int cidx = t * 256 + wv * 64 + l;    /* LDS slot this lane fills */        \
    srow[t] = cidx >> 3;                                                       \
    scg[t]  = (cidx & 7) ^ (srow[t] & 7); /* global chunk belonging there */   \
  }                                                                            \
  for (int kt = 0; kt < 8; ++kt) {                                             \
    const int k0 = kt * 64;                                                    \
    __syncthreads();                                                           \
    _Pragma("unroll")                                                          \
    for (int t = 0; t < 4; ++t) {                                              \
      gload_lds16(&A[(size_t)srow[t] * 512 + k0 + scg[t] * 8],                 \
                  &Al[(t * 256 + wv * 64) * 8]);                               \
      gload_lds16(&B[(size_t)srow[t] * 512 + k0 + scg[t] * 8],                 \
                  &Bl[(t * 256 + wv * 64) * 8]);                               \
    }                                                                          \
    __syncthreads();                                                           \
    _Pragma("unroll")                                                          \
    for (int ks = 0; ks < 2; ++ks) {                                           \
      bf16x8 af[4], bfr[4];                                                    \
      _Pragma("unroll")                                                        \
      for (int i = 0; i < 4; ++i) {                                            \
        int rA = wm * 64 + i * 16 + lc;                                        \
        int cA = (ks * 4 + lh) ^ (rA & 7);                                     \
        af[i] = *(const bf16x8*)&Al[(rA * 8 + cA) * 8];                        \
        int rB = wn * 64 + i * 16 + lc;                                        \
        int cB = (ks * 4 + lh) ^ (rB & 7);                                     \
        bfr[i] = *(const bf16x8*)&Bl[(rB * 8 + cB) * 8];                       \
      }                                                                        \
      _Pragma("unroll")                                                        \
      for (int i = 0; i < 4; ++i)                                              \
        _Pragma("unroll")                                                      \
        for (int j = 0; j < 4; ++j)                                            \
          acc[i][j] = __builtin_amdgcn_mfma_f32_16x16x32_bf16(af[i], bfr[j],   \
                                                              acc[i][j], 0, 0, 0); \
    }                                                                          \
  }

// QKV GEMM: A = qkv_w bf16 [1536][512]; B = h_t[b] [1024][512] ([n][c]).
__global__ __launch_bounds__(256) void qkv_gemm_kernel(const BF16* __restrict__ Wq,
                                                       const BF16* __restrict__ Ht,
                                                       const float* __restrict__ bias,
                                                       BF16* __restrict__ q_t,
                                                       BF16* __restrict__ k_t,
                                                       BF16* __restrict__ v_nat) {
  const int nt = blockIdx.x, mt = blockIdx.y, b = blockIdx.z;
  const int m0 = mt * 128, n0 = nt * 128;
  const BF16* A = Wq + (size_t)m0 * 512;
  const BF16* B = Ht + (size_t)b * 1024 * 512 + (size_t)n0 * 512;
  GEMM_PROLOGUE()

  const int r0 = lh * 4;
  #pragma unroll
  for (int mi = 0; mi < 4; ++mi) {
    const int o = m0 + wm * 64 + mi * 16 + r0;   // output row (o..o+3)
    #pragma unroll
    for (int ni = 0; ni < 4; ++ni) {
      const int pix = n0 + wn * 64 + ni * 16 + lc;
      f32x4 a = acc[mi][ni];
      if (mt < 8) {  // q or k: transposed store [bh][pix][d]
        const float scale = (mt < 4) ? 0.125f : 1.0f;
        const int hh = (o >> 6) & 7;
        const int d = o & 63;
        BF16* dst = (mt < 4 ? q_t : k_t) +
                    ((size_t)(b * 8 + hh) * 1024 + pix) * 64 + d;
        ushort4v pk;
        #pragma unroll
        for (int r = 0; r < 4; ++r) pk[r] = f2bf((a[r] + bias[o + r]) * scale);
        *(ushort4v*)dst = pk;
      } else {       // v: natural [b*512 + vr][pix]
        #pragma unroll
        for (int r = 0; r < 4; ++r) {
          const int vr = o + r - 1024;
          v_nat[((size_t)(b * 512 + vr)) * 1024 + pix] =
              __float2bfloat16(a[r] + bias[o + r]);
        }
      }
    }
  }
}

// Proj GEMM + bias + residual.
__global__ __launch_bounds__(256) void proj_gemm_kernel(const BF16* __restrict__ Wp,
                                                        const BF16* __restrict__ At,
                                                        const float* __restrict__ bias,
                                                        const float* __restrict__ x,
                                                        float* __restrict__ out) {
  const int nt = blockIdx.x, mt = blockIdx.y, b = blockIdx.z;
  const int m0 = mt * 128, n0 = nt * 128;
  const BF16* A = Wp + (size_t)m0 * 512;
  const BF16* B = At + (size_t)b * 1024 * 512 + (size_t)n0 * 512;
  GEMM_PROLOGUE()

  const int r0 = lh * 4;
  #pragma unroll
  for (int mi = 0; mi < 4; ++mi) {
    #pragma unroll
    for (int ni = 0; ni < 4; ++ni) {
      const int n = n0 + wn * 64 + ni * 16 + lc;
      f32x4 a = acc[mi][ni];
      #pragma unroll
      for (int r = 0; r < 4; ++r) {
        const int c = m0 + wm * 64 + mi * 16 + r0 + r;
        const size_t idx = ((size_t)(b * 512 + c)) * 1024 + n;
        out[idx] = x[idx] + bias[c] + a[r];
      }
    }
  }
}

// ---------------------------------------------------------------------------
// Kernel 4: flash attention, swapped-operand form.
// QK^T computed as mfma(A=K, B=Q) -> lane holds S[q=lc][j=16jf+4lh+r]: the
// whole softmax row is in ONE lane's lh-group -> in-lane max/sum + 2 shfls.
// PV computed as mfma(A=V^T, B=P) -> O[q=lc][d=16nf+4lh+r] in registers.
// K/V staged via global_load_lds into double-buffered LDS; next tile's loads
// issue right after the single per-iteration barrier and fly under compute.
// ---------------------------------------------------------------------------
__global__ __launch_bounds__(256) void attn_kernel(const BF16* __restrict__ q_t,
                                                   const BF16* __restrict__ k_t,
                                                   const BF16* __restrict__ v_nat,
                                                   BF16* __restrict__ attout) {
  const int bh = blockIdx.y;  // b*8 + h
  const int b = bh >> 3, hh = bh & 7;
  const int i0 = blockIdx.x * 64;
  const int tid = threadIdx.x, l = tid & 63, wv = tid >> 6;
  const int lc = l & 15, lh = l >> 4;

  __shared__ __align__(16) BF16 Kl[2][64 * 64];   // [j][d], chunk-swizzled
  __shared__ __align__(16) BF16 Vl[2][64 * 64];   // [d][j], chunk-swizzled
  __shared__ __align__(16) BF16 Pl[4][16][72];    // per-wave P [q][j], padded

  // Q as B-fragment: col=q=lc, k-chunk=lh
  bf16x8 aq0, aq1;
  {
    const BF16* qp = q_t + ((size_t)bh * 1024 + i0 + wv * 16 + lc) * 64;
    aq0 = *(const bf16x8*)&qp[lh * 8];
    aq1 = *(const bf16x8*)&qp[32 + lh * 8];
  }

  f32x4 O[4] = {};
  float mr = -1e30f, lr = 0.f;

  const BF16* kbase = k_t + (size_t)bh * 1024 * 64;
  const BF16* vbase = v_nat + (size_t)bh * 64 * 1024;

  // staging map (512 16B-chunks per tile, 2 rounds of 256 lanes)
  int srow[2], scg[2];
  #pragma unroll
  for (int it = 0; it < 2; ++it) {
    int cidx = it * 256 + wv * 64 + l;
    srow[it] = cidx >> 3;
    scg[it]  = (cidx & 7) ^ (srow[it] & 7);
  }

  // prefetch tile 0
  #pragma unroll
  for (int it = 0; it < 2; ++it) {
    gload_lds16(&kbase[(size_t)srow[it] * 64 + scg[it] * 8],
                &Kl[0][(it * 256 + wv * 64) * 8]);
    gload_lds16(&vbase[(size_t)srow[it] * 1024 + scg[it] * 8],
                &Vl[0][(it * 256 + wv * 64) * 8]);
  }

  for (int jt = 0; jt < 16; ++jt) {
    const int cur = jt & 1;
    __syncthreads();   // drains vmcnt -> tile jt resident; prev compute done
    if (jt < 15) {
      const int j1 = (jt + 1) * 64, nxt = cur ^ 1;
      #pragma unroll
      for (int it = 0; it < 2; ++it) {
        gload_lds16(&kbase[(size_t)(j1 + srow[it]) * 64 + scg[it] * 8],
                    &Kl[nxt][(it * 256 + wv * 64) * 8]);
        gload_lds16(&vbase[(size_t)srow[it] * 1024 + j1 + scg[it] * 8],
                    &Vl[nxt][(it * 256 + wv * 64) * 8]);
      }
    }

    // S^T: lane (lc,lh) -> S[q=lc][j=16jf+4lh+r]
    f32x4 Sv[4];
    __builtin_amdgcn_s_setprio(1);
    #pragma unroll
    for (int jf = 0; jf < 4; ++jf) {
      const int jl = jf * 16 + lc;
      int c0 = lh ^ (jl & 7);
      bf16x8 ak = *(const bf16x8*)&Kl[cur][(jl * 8 + c0) * 8];
      f32x4 s0 = {};
      s0 = __builtin_amdgcn_mfma_f32_16x16x32_bf16(ak, aq0, s0, 0, 0, 0);
      int c1 = (4 + lh) ^ (jl & 7);
      ak = *(const bf16x8*)&Kl[cur][(jl * 8 + c1) * 8];
      Sv[jf] = __builtin_amdgcn_mfma_f32_16x16x32_bf16(ak, aq1, s0, 0, 0, 0);
    }
    __builtin_amdgcn_s_setprio(0);

    // online softmax: in-lane over 16 values, then reduce over lh-group
    float tmax = Sv[0][0];
    #pragma unroll
    for (int jf = 0; jf < 4; ++jf)
      #pragma unroll
      for (int r = 0; r < 4; ++r) tmax = fmaxf(tmax, Sv[jf][r]);
    tmax = fmaxf(tmax, __shfl_xor(tmax, 16, 64));
    tmax = fmaxf(tmax, __shfl_xor(tmax, 32, 64));
    const float mnew = fmaxf(mr, tmax);
    const float sc = __expf(mr - mnew);
    mr = mnew;
    float rs = 0.f;
    float p[4][4];
    #pragma unroll
    for (int jf = 0; jf < 4; ++jf)
      #pragma unroll
      for (int r = 0; r < 4; ++r) {
        p[jf][r] = __expf(Sv[jf][r] - mnew);
        rs += p[jf][r];
      }
    rs += __shfl_xor(rs, 16, 64);
    rs += __shfl_xor(rs, 32, 64);
    lr = lr * sc + rs;
    #pragma unroll
    for (int nf = 0; nf < 4; ++nf)
      #pragma unroll
      for (int r = 0; r < 4; ++r) O[nf][r] *= sc;

    // stage P: row q=lc, cols 16jf+4lh+(0..3) -> 4 packed 8B writes
    #pragma unroll
    for (int jf = 0; jf < 4; ++jf) {
      ushort4v pk;
      #pragma unroll
      for (int r = 0; r < 4; ++r) pk[r] = f2bf(p[jf][r]);
      *(ushort4v*)&Pl[wv][lc][jf * 16 + 4 * lh] = pk;
    }
    // P as B-fragment: col=q=lc, k=j
    const bf16x8 bp0 = *(const bf16x8*)&Pl[wv][lc][lh * 8];
    const bf16x8 bp1 = *(const bf16x8*)&Pl[wv][lc][32 + lh * 8];

    // O^T[d][q] += V^T[d][j] * P[j][q]
    __builtin_amdgcn_s_setprio(1);
    #pragma unroll
    for (int nf = 0; nf < 4; ++nf) {
      const int dl = nf * 16 + lc;
      int c0 = lh ^ (dl & 7);
      bf16x8 av = *(const bf16x8*)&Vl[cur][(dl * 8 + c0) * 8];
      O[nf] = __builtin_amdgcn_mfma_f32_16x16x32_bf16(av, bp0, O[nf], 0, 0, 0);
      int c1 = (4 + lh) ^ (dl & 7);
      av = *(const bf16x8*)&Vl[cur][(dl * 8 + c1) * 8];
      O[nf] = __builtin_amdgcn_mfma_f32_16x16x32_bf16(av, bp1, O[nf], 0, 0, 0);
    }
    __builtin_amdgcn_s_setprio(0);
  }

  // epilogue: lane holds O[q=lc][d=16nf+4lh+r]
  const float inv = 1.0f / lr;
  BF16* dst = attout + ((size_t)b * 1024 + i0 + wv * 16 + lc) * 512 + hh * 64;
  #pragma unroll
  for (int nf = 0; nf < 4; ++nf) {
    ushort4v pk;
    #pragma unroll
    for (int r = 0; r < 4; ++r) pk[r] = f2bf(O[nf][r] * inv);
    *(ushort4v*)&dst[nf * 16 + 4 * lh] = pk;
  }
}

// ---------------------------------------------------------------------------
extern "C" void kernel_launch(void* const* d_in, const int* in_sizes, int n_in,
                              void* d_out, int out_size, void* d_ws, size_t ws_size,
                              hipStream_t stream) {
  const float* x      = (const float*)d_in[0];
  const float* gn_w   = (const float*)d_in[1];
  const float* gn_b   = (const float*)d_in[2];
  const float* qkv_w  = (const float*)d_in[3];
  const float* qkv_b  = (const float*)d_in[4];
  const float* proj_w = (const float*)d_in[5];
  const float* proj_b = (const float*)d_in[6];
  float* out = (float*)d_out;

  char* ws = (char*)d_ws;
  BF16* wq    = (BF16*)(ws);                     // 1.5 MB
  BF16* wp    = (BF16*)(ws + 1572864);           // 0.5 MB
  BF16* h_t   = (BF16*)(ws + 2097152);           // 8 MB
  BF16* q_t   = (BF16*)(ws + 10485760);          // 8 MB
  BF16* k_t   = (BF16*)(ws + 18874368);          // 8 MB
  BF16* v_nat = (BF16*)(ws + 27262976);          // 8 MB; end = 35651584
  BF16* attout = h_t;  // h_t dead after qkv GEMM; reuse for attention output

  cast_w_kernel<<<3072, 256, 0, stream>>>(qkv_w, proj_w, wq, wp);
  gn_kernel<<<256, 256, 0, stream>>>(x, gn_w, gn_b, h_t);
  qkv_gemm_kernel<<<dim3(8, 12, 8), 256, 0, stream>>>(wq, h_t, qkv_b, q_t, k_t, v_nat);
  attn_kernel<<<dim3(16, 64), 256, 0, stream>>>(q_t, k_t, v_nat, attout);
  proj_gemm_kernel<<<dim3(8, 4, 8), 256, 0, stream>>>(wp, attout, proj_b, x, out);
}

// Round 5
// 174.794 us; speedup vs baseline: 1.1101x; 1.0540x over previous
//
#include <hip/hip_runtime.h>
#include <hip/hip_bf16.h>

#define BF16 __hip_bfloat16

typedef __attribute__((ext_vector_type(8))) short bf16x8;
typedef __attribute__((ext_vector_type(4))) float f32x4;
typedef __attribute__((ext_vector_type(4))) unsigned short ushort4v;
typedef __attribute__((ext_vector_type(4))) float float4v;

__device__ __forceinline__ unsigned short f2bf(float f) {
  BF16 h = __float2bfloat16(f);
  union { BF16 h; unsigned short u; } cv;
  cv.h = h;
  return cv.u;
}

// Direct global->LDS async copy, 16B per lane. LDS dest is wave-uniform base
// + lane*16 (HW rule); swizzling is done on the GLOBAL source address.
__device__ __forceinline__ void gload_lds16(const BF16* g, BF16* s) {
  __builtin_amdgcn_global_load_lds(
      (const __attribute__((address_space(1))) void*)g,
      (__attribute__((address_space(3))) void*)s, 16, 0, 0);
}

// ---------------------------------------------------------------------------
// Kernel 1: cast weights fp32 -> bf16
// ---------------------------------------------------------------------------
__global__ __launch_bounds__(256) void cast_w_kernel(const float* __restrict__ qw,
                                                     const float* __restrict__ pw,
                                                     BF16* __restrict__ wq,
                                                     BF16* __restrict__ wp) {
  int i = blockIdx.x * 256 + threadIdx.x;
  if (i < 1536 * 512) wq[i] = __float2bfloat16(qw[i]);
  if (i < 512 * 512)  wp[i] = __float2bfloat16(pw[i]);
}

// ---------------------------------------------------------------------------
// Kernel 2: GroupNorm. One block per (batch, group); XCD-swizzled so that
// batch bb lands on XCD bb (h_t[bb] stays in that XCD's L2 for the QKV GEMM).
// Writes h transposed: h_t[b][n][c] bf16.
// ---------------------------------------------------------------------------
__global__ __launch_bounds__(256) void gn_kernel(const float* __restrict__ x,
                                                 const float* __restrict__ gw,
                                                 const float* __restrict__ gb,
                                                 BF16* __restrict__ h_t) {
  const int L = blockIdx.x;            // 0..255
  const int bb = L & 7, g = L >> 3;    // batch = XCD
  const float* xg = x + (size_t)(bb * 512 + g * 16) * 1024;  // 16 ch x 1024 px

  float s = 0.f, ss = 0.f;
  const float4v* x4 = (const float4v*)xg;
  for (int i = threadIdx.x; i < 4096; i += 256) {
    float4v v = x4[i];
    s  += v[0] + v[1] + v[2] + v[3];
    ss += v[0] * v[0] + v[1] * v[1] + v[2] * v[2] + v[3] * v[3];
  }
  for (int off = 32; off > 0; off >>= 1) {
    s  += __shfl_down(s, off, 64);
    ss += __shfl_down(ss, off, 64);
  }
  __shared__ float sred[8];
  const int wv = threadIdx.x >> 6;
  if ((threadIdx.x & 63) == 0) { sred[wv] = s; sred[4 + wv] = ss; }
  __syncthreads();
  const float S  = sred[0] + sred[1] + sred[2] + sred[3];
  const float SS = sred[4] + sred[5] + sred[6] + sred[7];
  const float mean = S * (1.f / 16384.f);
  const float var  = SS * (1.f / 16384.f) - mean * mean;
  const float rstd = rsqrtf(var + 1e-5f);

  const int ci = threadIdx.x & 15, nb = threadIdx.x >> 4;
  const int c  = g * 16 + ci;
  const float aw = gw[c] * rstd;
  const float ab = gb[c] - mean * aw;
  const float* xrow = xg + (size_t)ci * 1024;
  BF16* hb = h_t + (size_t)bb * 1024 * 512 + c;
  #pragma unroll 4
  for (int i = 0; i < 64; ++i) {
    int n = nb + i * 16;
    hb[(size_t)n * 512] = __float2bfloat16(aw * xrow[n] + ab);
  }
}

// ---------------------------------------------------------------------------
// GEMM core. Tile 128x128, BK=64, 4 waves (each 64x64), bf16 MFMA.
// Staging via global_load_lds (16B/lane); inverse chunk-XOR swizzle applied
// on the GLOBAL source address, LDS dest linear (m173 pattern).
// ---------------------------------------------------------------------------
#define GEMM_PROLOGUE()                                                        \
  const int tid = threadIdx.x, l = tid & 63, wv = tid >> 6;                    \
  const int wm = wv >> 1, wn = wv & 1;                                         \
  const int lc = l & 15, lh = l >> 4;                                          \
  __shared__ __align__(16) BF16 Al[128 * 64];                                  \
  __shared__ __align__(16) BF16 Bl[128 * 64];                                  \
  f32x4 acc[4][4] = {};                                                        \
  int srow[4], scg[4];                                                         \
  _Pragma("unroll")                                                            \
  for (int t = 0; t < 4; ++t) {                                                \
    int cidx = t * 256 + wv * 64 + l;                                          \
    srow[t] = cidx >> 3;                                                       \
    scg[t]  = (cidx & 7) ^ (srow[t] & 7);                                      \
  }                                                                            \
  for (int kt = 0; kt < 8; ++kt) {                                             \
    const int k0 = kt * 64;                                                    \
    __syncthreads();                                                           \
    _Pragma("unroll")                                                          \
    for (int t = 0; t < 4; ++t) {                                              \
      gload_lds16(&A[(size_t)srow[t] * 512 + k0 + scg[t] * 8],                 \
                  &Al[(t * 256 + wv * 64) * 8]);                               \
      gload_lds16(&B[(size_t)srow[t] * 512 + k0 + scg[t] * 8],                 \
                  &Bl[(t * 256 + wv * 64) * 8]);                               \
    }                                                                          \
    __syncthreads();                                                           \
    _Pragma("unroll")                                                          \
    for (int ks = 0; ks < 2; ++ks) {                                           \
      bf16x8 af[4], bfr[4];                                                    \
      _Pragma("unroll")                                                        \
      for (int i = 0; i < 4; ++i) {                                            \
        int rA = wm * 64 + i * 16 + lc;                                        \
        int cA = (ks * 4 + lh) ^ (rA & 7);                                     \
        af[i] = *(const bf16x8*)&Al[(rA * 8 + cA) * 8];                        \
        int rB = wn * 64 + i * 16 + lc;                                        \
        int cB = (ks * 4 + lh) ^ (rB & 7);                                     \
        bfr[i] = *(const bf16x8*)&Bl[(rB * 8 + cB) * 8];                       \
      }                                                                        \
      _Pragma("unroll")                                                        \
      for (int i = 0; i < 4; ++i)                                              \
        _Pragma("unroll")                                                      \
        for (int j = 0; j < 4; ++j)                                            \
          acc[i][j] = __builtin_amdgcn_mfma_f32_16x16x32_bf16(af[i], bfr[j],   \
                                                              acc[i][j], 0, 0, 0); \
    }                                                                          \
  }

// QKV GEMM: A = qkv_w bf16 [1536][512]; B = h_t[b] [1024][512] ([n][c]).
// XCD-swizzled 1D grid (768): batch b == XCD; 12 mt x 8 nt per batch.
__global__ __launch_bounds__(256) void qkv_gemm_kernel(const BF16* __restrict__ Wq,
                                                       const BF16* __restrict__ Ht,
                                                       const float* __restrict__ bias,
                                                       BF16* __restrict__ q_t,
                                                       BF16* __restrict__ k_t,
                                                       BF16* __restrict__ v_nat) {
  const int L = blockIdx.x;            // 0..767
  const int b = L & 7, w = L >> 3;     // batch = XCD
  const int mt = w % 12, nt = w / 12;
  const int m0 = mt * 128, n0 = nt * 128;
  const BF16* A = Wq + (size_t)m0 * 512;
  const BF16* B = Ht + (size_t)b * 1024 * 512 + (size_t)n0 * 512;
  GEMM_PROLOGUE()

  const int r0 = lh * 4;
  #pragma unroll
  for (int mi = 0; mi < 4; ++mi) {
    const int o = m0 + wm * 64 + mi * 16 + r0;   // output row (o..o+3)
    #pragma unroll
    for (int ni = 0; ni < 4; ++ni) {
      const int pix = n0 + wn * 64 + ni * 16 + lc;
      f32x4 a = acc[mi][ni];
      if (mt < 8) {  // q or k: transposed store [bh][pix][d]
        const float scale = (mt < 4) ? 0.125f : 1.0f;
        const int hh = (o >> 6) & 7;
        const int d = o & 63;
        BF16* dst = (mt < 4 ? q_t : k_t) +
                    ((size_t)(b * 8 + hh) * 1024 + pix) * 64 + d;
        ushort4v pk;
        #pragma unroll
        for (int r = 0; r < 4; ++r) pk[r] = f2bf((a[r] + bias[o + r]) * scale);
        *(ushort4v*)dst = pk;
      } else {       // v: natural [b*512 + vr][pix]
        #pragma unroll
        for (int r = 0; r < 4; ++r) {
          const int vr = o + r - 1024;
          v_nat[((size_t)(b * 512 + vr)) * 1024 + pix] =
              __float2bfloat16(a[r] + bias[o + r]);
        }
      }
    }
  }
}

// Proj GEMM + bias + residual. XCD-swizzled 1D grid (256): batch == XCD.
__global__ __launch_bounds__(256) void proj_gemm_kernel(const BF16* __restrict__ Wp,
                                                        const BF16* __restrict__ At,
                                                        const float* __restrict__ bias,
                                                        const float* __restrict__ x,
                                                        float* __restrict__ out) {
  const int L = blockIdx.x;            // 0..255
  const int b = L & 7, w = L >> 3;
  const int mt = w & 3, nt = w >> 2;
  const int m0 = mt * 128, n0 = nt * 128;
  const BF16* A = Wp + (size_t)m0 * 512;
  const BF16* B = At + (size_t)b * 1024 * 512 + (size_t)n0 * 512;
  GEMM_PROLOGUE()

  const int r0 = lh * 4;
  #pragma unroll
  for (int mi = 0; mi < 4; ++mi) {
    #pragma unroll
    for (int ni = 0; ni < 4; ++ni) {
      const int n = n0 + wn * 64 + ni * 16 + lc;
      f32x4 a = acc[mi][ni];
      #pragma unroll
      for (int r = 0; r < 4; ++r) {
        const int c = m0 + wm * 64 + mi * 16 + r0 + r;
        const size_t idx = ((size_t)(b * 512 + c)) * 1024 + n;
        out[idx] = x[idx] + bias[c] + a[r];
      }
    }
  }
}

// ---------------------------------------------------------------------------
// Kernel 4: flash attention, swapped-operand form, 128 q-rows per block.
// Each wave owns 32 q-rows as two 16-col blocks (cb=0,1); K/V LDS fragments
// are read ONCE per iteration and shared across both cb's (halves DS traffic
// per q vs one cb). Online softmax fully per-lane + 2 shfls; defer-max
// (THR=8) skips the O-rescale pass when the running max doesn't grow.
// XCD-swizzled: batch == XCD so K/V/Q stay L2-resident.
// ---------------------------------------------------------------------------
__global__ __launch_bounds__(256) void attn_kernel(const BF16* __restrict__ q_t,
                                                   const BF16* __restrict__ k_t,
                                                   const BF16* __restrict__ v_nat,
                                                   BF16* __restrict__ attout) {
  const int L = blockIdx.x;            // 0..511
  const int xcd = L & 7, w = L >> 3;
  const int b = xcd, hh = w & 7;       // batch = XCD
  const int bh = b * 8 + hh;
  const int i0 = (w >> 3) * 128;
  const int tid = threadIdx.x, l = tid & 63, wv = tid >> 6;
  const int lc = l & 15, lh = l >> 4;

  __shared__ __align__(16) BF16 Kl[2][64 * 64];   // [j][d], chunk-swizzled
  __shared__ __align__(16) BF16 Vl[2][64 * 64];   // [d][j], chunk-swizzled
  __shared__ __align__(16) BF16 Pl[4][2][16][72]; // per-wave/cb P [q][j]

  // Q as B-fragment: col=q=lc, k-chunk=lh; two col-blocks per wave
  bf16x8 aq[2][2];
  #pragma unroll
  for (int cb = 0; cb < 2; ++cb) {
    const BF16* qp = q_t + ((size_t)bh * 1024 + i0 + wv * 32 + cb * 16 + lc) * 64;
    aq[cb][0] = *(const bf16x8*)&qp[lh * 8];
    aq[cb][1] = *(const bf16x8*)&qp[32 + lh * 8];
  }

  f32x4 O[2][4] = {};
  float mr[2] = {-1e30f, -1e30f}, lr[2] = {0.f, 0.f};

  const BF16* kbase = k_t + (size_t)bh * 1024 * 64;
  const BF16* vbase = v_nat + (size_t)bh * 64 * 1024;

  // staging map (512 16B-chunks per tile, 2 rounds of 256 lanes)
  int srow[2], scg[2];
  #pragma unroll
  for (int it = 0; it < 2; ++it) {
    int cidx = it * 256 + wv * 64 + l;
    srow[it] = cidx >> 3;
    scg[it]  = (cidx & 7) ^ (srow[it] & 7);
  }

  // prefetch tile 0
  #pragma unroll
  for (int it = 0; it < 2; ++it) {
    gload_lds16(&kbase[(size_t)srow[it] * 64 + scg[it] * 8],
                &Kl[0][(it * 256 + wv * 64) * 8]);
    gload_lds16(&vbase[(size_t)srow[it] * 1024 + scg[it] * 8],
                &Vl[0][(it * 256 + wv * 64) * 8]);
  }

  for (int jt = 0; jt < 16; ++jt) {
    const int cur = jt & 1;
    __syncthreads();   // tile jt resident; prev compute done
    if (jt < 15) {
      const int j1 = (jt + 1) * 64, nxt = cur ^ 1;
      #pragma unroll
      for (int it = 0; it < 2; ++it) {
        gload_lds16(&kbase[(size_t)(j1 + srow[it]) * 64 + scg[it] * 8],
                    &Kl[nxt][(it * 256 + wv * 64) * 8]);
        gload_lds16(&vbase[(size_t)srow[it] * 1024 + j1 + scg[it] * 8],
                    &Vl[nxt][(it * 256 + wv * 64) * 8]);
      }
    }

    // S^T for both col-blocks; K fragments read once, shared
    f32x4 Sv[2][4];
    __builtin_amdgcn_s_setprio(1);
    #pragma unroll
    for (int jf = 0; jf < 4; ++jf) {
      const int jl = jf * 16 + lc;
      const int c0 = lh ^ (jl & 7), c1 = (4 + lh) ^ (jl & 7);
      bf16x8 ak0 = *(const bf16x8*)&Kl[cur][(jl * 8 + c0) * 8];
      bf16x8 ak1 = *(const bf16x8*)&Kl[cur][(jl * 8 + c1) * 8];
      #pragma unroll
      for (int cb = 0; cb < 2; ++cb) {
        f32x4 s0 = {};
        s0 = __builtin_amdgcn_mfma_f32_16x16x32_bf16(ak0, aq[cb][0], s0, 0, 0, 0);
        Sv[cb][jf] = __builtin_amdgcn_mfma_f32_16x16x32_bf16(ak1, aq[cb][1], s0, 0, 0, 0);
      }
    }
    __builtin_amdgcn_s_setprio(0);

    // online softmax per col-block (defer-max THR=8), stage P to LDS
    #pragma unroll
    for (int cb = 0; cb < 2; ++cb) {
      float tmax = Sv[cb][0][0];
      #pragma unroll
      for (int jf = 0; jf < 4; ++jf)
        #pragma unroll
        for (int r = 0; r < 4; ++r) tmax = fmaxf(tmax, Sv[cb][jf][r]);
      tmax = fmaxf(tmax, __shfl_xor(tmax, 16, 64));
      tmax = fmaxf(tmax, __shfl_xor(tmax, 32, 64));
      if (__any(tmax > mr[cb] + 8.f)) {
        const float mnew = fmaxf(mr[cb], tmax);
        const float sc = __expf(mr[cb] - mnew);
        mr[cb] = mnew;
        lr[cb] *= sc;
        #pragma unroll
        for (int nf = 0; nf < 4; ++nf)
          #pragma unroll
          for (int r = 0; r < 4; ++r) O[cb][nf][r] *= sc;
      }
      float rs = 0.f;
      #pragma unroll
      for (int jf = 0; jf < 4; ++jf) {
        ushort4v pk;
        #pragma unroll
        for (int r = 0; r < 4; ++r) {
          float p = __expf(Sv[cb][jf][r] - mr[cb]);
          rs += p;
          pk[r] = f2bf(p);
        }
        *(ushort4v*)&Pl[wv][cb][lc][jf * 16 + 4 * lh] = pk;
      }
      rs += __shfl_xor(rs, 16, 64);
      rs += __shfl_xor(rs, 32, 64);
      lr[cb] += rs;
    }

    // P as B-fragment for both cb
    bf16x8 bp[2][2];
    #pragma unroll
    for (int cb = 0; cb < 2; ++cb) {
      bp[cb][0] = *(const bf16x8*)&Pl[wv][cb][lc][lh * 8];
      bp[cb][1] = *(const bf16x8*)&Pl[wv][cb][lc][32 + lh * 8];
    }

    // O^T[d][q] += V^T[d][j] * P[j][q]; V fragments read once, shared
    __builtin_amdgcn_s_setprio(1);
    #pragma unroll
    for (int nf = 0; nf < 4; ++nf) {
      const int dl = nf * 16 + lc;
      const int c0 = lh ^ (dl & 7), c1 = (4 + lh) ^ (dl & 7);
      bf16x8 av0 = *(const bf16x8*)&Vl[cur][(dl * 8 + c0) * 8];
      bf16x8 av1 = *(const bf16x8*)&Vl[cur][(dl * 8 + c1) * 8];
      #pragma unroll
      for (int cb = 0; cb < 2; ++cb) {
        O[cb][nf] = __builtin_amdgcn_mfma_f32_16x16x32_bf16(av0, bp[cb][0], O[cb][nf], 0, 0, 0);
        O[cb][nf] = __builtin_amdgcn_mfma_f32_16x16x32_bf16(av1, bp[cb][1], O[cb][nf], 0, 0, 0);
      }
    }
    __builtin_amdgcn_s_setprio(0);
  }

  // epilogue: lane holds O[q=lc][d=16nf+4lh+r] per cb
  #pragma unroll
  for (int cb = 0; cb < 2; ++cb) {
    const float inv = 1.0f / lr[cb];
    BF16* dst = attout + ((size_t)b * 1024 + i0 + wv * 32 + cb * 16 + lc) * 512 + hh * 64;
    #pragma unroll
    for (int nf = 0; nf < 4; ++nf) {
      ushort4v pk;
      #pragma unroll
      for (int r = 0; r < 4; ++r) pk[r] = f2bf(O[cb][nf][r] * inv);
      *(ushort4v*)&dst[nf * 16 + 4 * lh] = pk;
    }
  }
}

// ---------------------------------------------------------------------------
extern "C" void kernel_launch(void* const* d_in, const int* in_sizes, int n_in,
                              void* d_out, int out_size, void* d_ws, size_t ws_size,
                              hipStream_t stream) {
  const float* x      = (const float*)d_in[0];
  const float* gn_w   = (const float*)d_in[1];
  const float* gn_b   = (const float*)d_in[2];
  const float* qkv_w  = (const float*)d_in[3];
  const float* qkv_b  = (const float*)d_in[4];
  const float* proj_w = (const float*)d_in[5];
  const float* proj_b = (const float*)d_in[6];
  float* out = (float*)d_out;

  char* ws = (char*)d_ws;
  BF16* wq    = (BF16*)(ws);                     // 1.5 MB
  BF16* wp    = (BF16*)(ws + 1572864);           // 0.5 MB
  BF16* h_t   = (BF16*)(ws + 2097152);           // 8 MB
  BF16* q_t   = (BF16*)(ws + 10485760);          // 8 MB
  BF16* k_t   = (BF16*)(ws + 18874368);          // 8 MB
  BF16* v_nat = (BF16*)(ws + 27262976);          // 8 MB; end = 35651584
  BF16* attout = h_t;  // h_t dead after qkv GEMM; reuse for attention output

  cast_w_kernel<<<3072, 256, 0, stream>>>(qkv_w, proj_w, wq, wp);
  gn_kernel<<<256, 256, 0, stream>>>(x, gn_w, gn_b, h_t);
  qkv_gemm_kernel<<<768, 256, 0, stream>>>(wq, h_t, qkv_b, q_t, k_t, v_nat);
  attn_kernel<<<512, 256, 0, stream>>>(q_t, k_t, v_nat, attout);
  proj_gemm_kernel<<<256, 256, 0, stream>>>(wp, attout, proj_b, x, out);
}

// Round 7
// 171.276 us; speedup vs baseline: 1.1329x; 1.0205x over previous
//
#include <hip/hip_runtime.h>
#include <hip/hip_bf16.h>

#define BF16 __hip_bfloat16

typedef __attribute__((ext_vector_type(8))) short bf16x8;
typedef __attribute__((ext_vector_type(4))) float f32x4;
typedef __attribute__((ext_vector_type(4))) unsigned short ushort4v;
typedef __attribute__((ext_vector_type(4))) float float4v;

#define LOG2E 1.44269504089f

__device__ __forceinline__ unsigned short f2bf(float f) {
  BF16 h = __float2bfloat16(f);
  union { BF16 h; unsigned short u; } cv;
  cv.h = h;
  return cv.u;
}

// Direct global->LDS async copy, 16B per lane. LDS dest is wave-uniform base
// + lane*16 (HW rule); swizzling is done on the GLOBAL source address.
__device__ __forceinline__ void gload_lds16(const BF16* g, BF16* s) {
  __builtin_amdgcn_global_load_lds(
      (const __attribute__((address_space(1))) void*)g,
      (__attribute__((address_space(3))) void*)s, 16, 0, 0);
}

// ---------------------------------------------------------------------------
// Kernel 1: fused GroupNorm stats (+per-channel affine precompute) and
// weight fp32->bf16 casts. Blocks [0,256): stats for (b,g) -> stats[b][c] =
// {aw, ab}. Blocks [256,1280): vectorized weight casts.
// ---------------------------------------------------------------------------
__global__ __launch_bounds__(256) void stats_cast_kernel(const float* __restrict__ x,
                                                         const float* __restrict__ gw,
                                                         const float* __restrict__ gb,
                                                         const float* __restrict__ qw,
                                                         const float* __restrict__ pw,
                                                         float2* __restrict__ stats,
                                                         BF16* __restrict__ wq,
                                                         BF16* __restrict__ wp) {
  const int L = blockIdx.x;
  if (L < 256) {
    const int bb = L & 7, g = L >> 3;   // batch = XCD
    const float* xg = x + (size_t)(bb * 512 + g * 16) * 1024;
    float s = 0.f, ss = 0.f;
    const float4v* x4 = (const float4v*)xg;
    for (int i = threadIdx.x; i < 4096; i += 256) {
      float4v v = x4[i];
      s  += v[0] + v[1] + v[2] + v[3];
      ss += v[0] * v[0] + v[1] * v[1] + v[2] * v[2] + v[3] * v[3];
    }
    for (int off = 32; off > 0; off >>= 1) {
      s  += __shfl_down(s, off, 64);
      ss += __shfl_down(ss, off, 64);
    }
    __shared__ float sred[8];
    const int wv = threadIdx.x >> 6;
    if ((threadIdx.x & 63) == 0) { sred[wv] = s; sred[4 + wv] = ss; }
    __syncthreads();
    const float S  = sred[0] + sred[1] + sred[2] + sred[3];
    const float SS = sred[4] + sred[5] + sred[6] + sred[7];
    const float mean = S * (1.f / 16384.f);
    const float var  = SS * (1.f / 16384.f) - mean * mean;
    const float rstd = rsqrtf(var + 1e-5f);
    if (threadIdx.x < 16) {
      const int c = g * 16 + threadIdx.x;
      const float aw = gw[c] * rstd;
      float2 st; st.x = aw; st.y = gb[c] - mean * aw;
      stats[bb * 512 + c] = st;
    }
  } else {
    const int i4 = (L - 256) * 256 + threadIdx.x;  // float4 index
    if (i4 < 196608) {            // qkv_w: 1536*512/4
      float4v v = ((const float4v*)qw)[i4];
      ushort4v pk;
      #pragma unroll
      for (int r = 0; r < 4; ++r) pk[r] = f2bf(v[r]);
      *(ushort4v*)&wq[i4 * 4] = pk;
    } else {                      // proj_w: 512*512/4
      const int j = i4 - 196608;
      float4v v = ((const float4v*)pw)[j];
      ushort4v pk;
      #pragma unroll
      for (int r = 0; r < 4; ++r) pk[r] = f2bf(v[r]);
      *(ushort4v*)&wp[j * 4] = pk;
    }
  }
}

// ---------------------------------------------------------------------------
// Kernel 2: GroupNorm apply + transpose. Block owns (batch, 32-px tile) x ALL
// 512 channels -> h_t[b][n][c] rows written as coalesced 256B chunks.
// LDS transpose per 128-ch tile with granule XOR (read-side conflict-free).
// ---------------------------------------------------------------------------
__global__ __launch_bounds__(256) void gn_apply_kernel(const float* __restrict__ x,
                                                       const float2* __restrict__ stats,
                                                       BF16* __restrict__ h_t) {
  const int L = blockIdx.x;           // 0..255
  const int b = L & 7, pxt = L >> 3;  // batch = XCD; 32 px per tile
  const int t = threadIdx.x;
  __shared__ __align__(16) BF16 Lt[128 * 8 * 4];  // 128 ch x 32 px, 8B granules

  for (int ct = 0; ct < 4; ++ct) {    // 128-channel tiles
    if (ct) __syncthreads();
    #pragma unroll
    for (int k = 0; k < 4; ++k) {
      const int i = k * 256 + t;
      const int ch_l = i >> 3, f4l = i & 7;
      const int cg = ct * 128 + ch_l;
      const float2 st = stats[b * 512 + cg];
      const float4v v =
          ((const float4v*)x)[((size_t)(b * 512 + cg)) * 256 + pxt * 8 + f4l];
      ushort4v pk;
      #pragma unroll
      for (int r = 0; r < 4; ++r) pk[r] = f2bf(v[r] * st.x + st.y);
      const int s = f4l ^ (ch_l & 7) ^ ((ch_l >> 3) & 7);
      *(ushort4v*)&Lt[(ch_l * 8 + s) * 4] = pk;
    }
    __syncthreads();
    #pragma unroll
    for (int rr = 0; rr < 2; ++rr) {
      const int px_l = (rr * 256 + t) >> 4;   // 0..31
      const int c16 = t & 15;
      union { unsigned short u[8]; bf16x8 v8; } o;
      #pragma unroll
      for (int cc = 0; cc < 8; ++cc) {
        const int ch = c16 * 8 + cc;
        const int s = (px_l >> 2) ^ (ch & 7) ^ ((ch >> 3) & 7);
        o.u[cc] = *(const unsigned short*)&Lt[(ch * 8 + s) * 4 + (px_l & 3)];
      }
      *(bf16x8*)&h_t[((size_t)(b * 1024 + pxt * 32 + px_l)) * 512 + ct * 128 +
                     c16 * 8] = o.v8;
    }
  }
}

// ---------------------------------------------------------------------------
// GEMM core. Tile 128x128, BK=64, 4 waves, bf16 MFMA; global_load_lds staging
// with inverse chunk-XOR on the global source (m173 pattern). Al/Bl supplied
// by the caller so the epilogue can reuse the 32 KiB for output transpose.
// ---------------------------------------------------------------------------
#define GEMM_CORE(A, B, Al, Bl)                                                \
  const int tid = threadIdx.x, l = tid & 63, wv = tid >> 6;                    \
  const int wm = wv >> 1, wn = wv & 1;                                         \
  const int lc = l & 15, lh = l >> 4;                                          \
  f32x4 acc[4][4] = {};                                                        \
  int srow[4], scg[4];                                                         \
  _Pragma("unroll")                                                            \
  for (int t = 0; t < 4; ++t) {                                                \
    int cidx = t * 256 + wv * 64 + l;                                          \
    srow[t] = cidx >> 3;                                                       \
    scg[t]  = (cidx & 7) ^ (srow[t] & 7);                                      \
  }                                                                            \
  for (int kt = 0; kt < 8; ++kt) {                                             \
    const int k0 = kt * 64;                                                    \
    __syncthreads();                                                           \
    _Pragma("unroll")                                                          \
    for (int t = 0; t < 4; ++t) {                                              \
      gload_lds16(&A[(size_t)srow[t] * 512 + k0 + scg[t] * 8],                 \
                  &Al[(t * 256 + wv * 64) * 8]);                               \
      gload_lds16(&B[(size_t)srow[t] * 512 + k0 + scg[t] * 8],                 \
                  &Bl[(t * 256 + wv * 64) * 8]);                               \
    }                                                                          \
    __syncthreads();                                                           \
    _Pragma("unroll")                                                          \
    for (int ks = 0; ks < 2; ++ks) {                                           \
      bf16x8 af[4], bfr[4];                                                    \
      _Pragma("unroll")                                                        \
      for (int i = 0; i < 4; ++i) {                                            \
        int rA = wm * 64 + i * 16 + lc;                                        \
        int cA = (ks * 4 + lh) ^ (rA & 7);                                     \
        af[i] = *(const bf16x8*)&Al[(rA * 8 + cA) * 8];                        \
        int rB = wn * 64 + i * 16 + lc;                                        \
        int cB = (ks * 4 + lh) ^ (rB & 7);                                     \
        bfr[i] = *(const bf16x8*)&Bl[(rB * 8 + cB) * 8];                       \
      }                                                                        \
      _Pragma("unroll")                                                        \
      for (int i = 0; i < 4; ++i)                                              \
        _Pragma("unroll")                                                      \
        for (int j = 0; j < 4; ++j)                                            \
          acc[i][j] = __builtin_amdgcn_mfma_f32_16x16x32_bf16(af[i], bfr[j],   \
                                                              acc[i][j], 0, 0, 0); \
    }                                                                          \
  }

// QKV GEMM: A = qkv_w bf16 [1536][512]; B = h_t[b] [1024][512].
// Epilogue stages the output tile in LDS (granule-XOR) and writes fully
// coalesced: Q/K as [bh][pix][d] 1KB runs, V as [b c][pix] 256B runs.
// Q pre-scaled by 0.125*log2(e) (attn uses exp2 directly).
__global__ __launch_bounds__(256) void qkv_gemm_kernel(const BF16* __restrict__ Wq,
                                                       const BF16* __restrict__ Ht,
                                                       const float* __restrict__ bias,
                                                       BF16* __restrict__ q_t,
                                                       BF16* __restrict__ k_t,
                                                       BF16* __restrict__ v_nat) {
  const int L = blockIdx.x;            // 0..767
  const int b = L & 7, w = L >> 3;     // batch = XCD
  const int mt = w % 12, nt = w / 12;
  const int m0 = mt * 128, n0 = nt * 128;
  const BF16* A = Wq + (size_t)m0 * 512;
  const BF16* B = Ht + (size_t)b * 1024 * 512 + (size_t)n0 * 512;
  __shared__ __align__(16) BF16 smem[16384];
  BF16* Al = smem;
  BF16* Bl = smem + 8192;
  GEMM_CORE(A, B, Al, Bl)

  // ---- epilogue: bias(+scale) -> LDS transpose -> coalesced stores ----
  __syncthreads();                     // all frag reads done; reuse smem
  BF16* Et = smem;                     // 16384 BF16 = 32 KiB
  if (mt < 8) {
    const float scale = (mt < 4) ? 0.125f * LOG2E : 1.0f;
    #pragma unroll
    for (int mi = 0; mi < 4; ++mi) {
      const int d0 = mi * 16 + 4 * lh;          // 0..63
      const int o  = m0 + wm * 64 + d0;
      const int g  = d0 >> 3;
      #pragma unroll
      for (int ni = 0; ni < 4; ++ni) {
        const int pixl = wn * 64 + ni * 16 + lc;
        f32x4 a = acc[mi][ni];
        ushort4v pk;
        #pragma unroll
        for (int r = 0; r < 4; ++r) pk[r] = f2bf((a[r] + bias[o + r]) * scale);
        const int s = g ^ (pixl & 7);
        *(ushort4v*)&Et[((wm * 128 + pixl) * 8 + s) * 8 + (d0 & 7)] = pk;
      }
    }
    __syncthreads();
    BF16* dstb = (mt < 4) ? q_t : k_t;
    const int hb0 = (mt & 3) * 2;
    #pragma unroll
    for (int rr = 0; rr < 8; ++rr) {
      const int rowI = rr * 32 + (tid >> 3);    // 0..255
      const int h2 = rowI >> 7, pixl = rowI & 127;
      const int j = tid & 7;
      bf16x8 v = *(const bf16x8*)&Et[(rowI * 8 + (j ^ (pixl & 7))) * 8];
      *(bf16x8*)&dstb[((size_t)(b * 8 + hb0 + h2) * 1024 + n0 + pixl) * 64 +
                      j * 8] = v;
    }
  } else {
    // V: stage [vr_l][pixl] (128x128)
    #pragma unroll
    for (int mi = 0; mi < 4; ++mi) {
      #pragma unroll
      for (int ni = 0; ni < 4; ++ni) {
        const int pixl = wn * 64 + ni * 16 + lc;
        const int gp = pixl >> 3;
        f32x4 a = acc[mi][ni];
        #pragma unroll
        for (int r = 0; r < 4; ++r) {
          const int vr_l = wm * 64 + mi * 16 + 4 * lh + r;
          const int s = gp ^ (vr_l & 15);
          Et[(vr_l * 16 + s) * 8 + (pixl & 7)] =
              __float2bfloat16(a[r] + bias[m0 + vr_l]);
        }
      }
    }
    __syncthreads();
    const int vr0 = m0 - 1024;
    #pragma unroll
    for (int rr = 0; rr < 8; ++rr) {
      const int vr_l = rr * 16 + (tid >> 4);
      const int gp = tid & 15;
      bf16x8 v = *(const bf16x8*)&Et[(vr_l * 16 + (gp ^ (vr_l & 15))) * 8];
      *(bf16x8*)&v_nat[((size_t)(b * 512 + vr0 + vr_l)) * 1024 + n0 + gp * 8] = v;
    }
  }
}

// Proj GEMM + bias + residual. XCD-swizzled: batch == XCD.
__global__ __launch_bounds__(256) void proj_gemm_kernel(const BF16* __restrict__ Wp,
                                                        const BF16* __restrict__ At,
                                                        const float* __restrict__ bias,
                                                        const float* __restrict__ x,
                                                        float* __restrict__ out) {
  const int L = blockIdx.x;            // 0..255
  const int b = L & 7, w = L >> 3;
  const int mt = w & 3, nt = w >> 2;
  const int m0 = mt * 128, n0 = nt * 128;
  const BF16* A = Wp + (size_t)m0 * 512;
  const BF16* B = At + (size_t)b * 1024 * 512 + (size_t)n0 * 512;
  __shared__ __align__(16) BF16 smem[16384];
  BF16* Al = smem;
  BF16* Bl = smem + 8192;
  GEMM_CORE(A, B, Al, Bl)

  const int r0 = lh * 4;
  #pragma unroll
  for (int mi = 0; mi < 4; ++mi) {
    #pragma unroll
    for (int ni = 0; ni < 4; ++ni) {
      const int n = n0 + wn * 64 + ni * 16 + lc;
      f32x4 a = acc[mi][ni];
      #pragma unroll
      for (int r = 0; r < 4; ++r) {
        const int c = m0 + wm * 64 + mi * 16 + r0 + r;
        const size_t idx = ((size_t)(b * 512 + c)) * 1024 + n;
        out[idx] = x[idx] + bias[c] + a[r];
      }
    }
  }
}

// ---------------------------------------------------------------------------
// Kernel 4: flash attention, swapped-operand form, 128 q-rows per block.
// S is in log2-domain (Q pre-scaled by 0.125*log2e) -> exp2 directly.
// Defer-max threshold 8*log2e ~= 11.52.
// ---------------------------------------------------------------------------
__global__ __launch_bounds__(256) void attn_kernel(const BF16* __restrict__ q_t,
                                                   const BF16* __restrict__ k_t,
                                                   const BF16* __restrict__ v_nat,
                                                   BF16* __restrict__ attout) {
  const int L = blockIdx.x;            // 0..511
  const int xcd = L & 7, w = L >> 3;
  const int b = xcd, hh = w & 7;       // batch = XCD
  const int bh = b * 8 + hh;
  const int i0 = (w >> 3) * 128;
  const int tid = threadIdx.x, l = tid & 63, wv = tid >> 6;
  const int lc = l & 15, lh = l >> 4;

  __shared__ __align__(16) BF16 Kl[2][64 * 64];   // [j][d], chunk-swizzled
  __shared__ __align__(16) BF16 Vl[2][64 * 64];   // [d][j], chunk-swizzled
  __shared__ __align__(16) BF16 Pl[4][2][16][72]; // per-wave/cb P [q][j]

  bf16x8 aq[2][2];
  #pragma unroll
  for (int cb = 0; cb < 2; ++cb) {
    const BF16* qp = q_t + ((size_t)bh * 1024 + i0 + wv * 32 + cb * 16 + lc) * 64;
    aq[cb][0] = *(const bf16x8*)&qp[lh * 8];
    aq[cb][1] = *(const bf16x8*)&qp[32 + lh * 8];
  }

  f32x4 O[2][4] = {};
  float mr[2] = {-1e30f, -1e30f}, lr[2] = {0.f, 0.f};

  const BF16* kbase = k_t + (size_t)bh * 1024 * 64;
  const BF16* vbase = v_nat + (size_t)bh * 64 * 1024;

  int srow[2], scg[2];
  #pragma unroll
  for (int it = 0; it < 2; ++it) {
    int cidx = it * 256 + wv * 64 + l;
    srow[it] = cidx >> 3;
    scg[it]  = (cidx & 7) ^ (srow[it] & 7);
  }

  #pragma unroll
  for (int it = 0; it < 2; ++it) {
    gload_lds16(&kbase[(size_t)srow[it] * 64 + scg[it] * 8],
                &Kl[0][(it * 256 + wv * 64) * 8]);
    gload_lds16(&vbase[(size_t)srow[it] * 1024 + scg[it] * 8],
                &Vl[0][(it * 256 + wv * 64) * 8]);
  }

  for (int jt = 0; jt < 16; ++jt) {
    const int cur = jt & 1;
    __syncthreads();
    if (jt < 15) {
      const int j1 = (jt + 1) * 64, nxt = cur ^ 1;
      #pragma unroll
      for (int it = 0; it < 2; ++it) {
        gload_lds16(&kbase[(size_t)(j1 + srow[it]) * 64 + scg[it] * 8],
                    &Kl[nxt][(it * 256 + wv * 64) * 8]);
        gload_lds16(&vbase[(size_t)srow[it] * 1024 + j1 + scg[it] * 8],
                    &Vl[nxt][(it * 256 + wv * 64) * 8]);
      }
    }

    f32x4 Sv[2][4];
    __builtin_amdgcn_s_setprio(1);
    #pragma unroll
    for (int jf = 0; jf < 4; ++jf) {
      const int jl = jf * 16 + lc;
      const int c0 = lh ^ (jl & 7), c1 = (4 + lh) ^ (jl & 7);
      bf16x8 ak0 = *(const bf16x8*)&Kl[cur][(jl * 8 + c0) * 8];
      bf16x8 ak1 = *(const bf16x8*)&Kl[cur][(jl * 8 + c1) * 8];
      #pragma unroll
      for (int cb = 0; cb < 2; ++cb) {
        f32x4 s0 = {};
        s0 = __builtin_amdgcn_mfma_f32_16x16x32_bf16(ak0, aq[cb][0], s0, 0, 0, 0);
        Sv[cb][jf] = __builtin_amdgcn_mfma_f32_16x16x32_bf16(ak1, aq[cb][1], s0, 0, 0, 0);
      }
    }
    __builtin_amdgcn_s_setprio(0);

    #pragma unroll
    for (int cb = 0; cb < 2; ++cb) {
      float tmax = Sv[cb][0][0];
      #pragma unroll
      for (int jf = 0; jf < 4; ++jf)
        #pragma unroll
        for (int r = 0; r < 4; ++r) tmax = fmaxf(tmax, Sv[cb][jf][r]);
      tmax = fmaxf(tmax, __shfl_xor(tmax, 16, 64));
      tmax = fmaxf(tmax, __shfl_xor(tmax, 32, 64));
      if (__any(tmax > mr[cb] + 11.52f)) {
        const float mnew = fmaxf(mr[cb], tmax);
        const float sc = exp2f(mr[cb] - mnew);
        mr[cb] = mnew;
        lr[cb] *= sc;
        #pragma unroll
        for (int nf = 0; nf < 4; ++nf)
          #pragma unroll
          for (int r = 0; r < 4; ++r) O[cb][nf][r] *= sc;
      }
      float rs = 0.f;
      #pragma unroll
      for (int jf = 0; jf < 4; ++jf) {
        ushort4v pk;
        #pragma unroll
        for (int r = 0; r < 4; ++r) {
          float p = exp2f(Sv[cb][jf][r] - mr[cb]);
          rs += p;
          pk[r] = f2bf(p);
        }
        *(ushort4v*)&Pl[wv][cb][lc][jf * 16 + 4 * lh] = pk;
      }
      rs += __shfl_xor(rs, 16, 64);
      rs += __shfl_xor(rs, 32, 64);
      lr[cb] += rs;
    }

    bf16x8 bp[2][2];
    #pragma unroll
    for (int cb = 0; cb < 2; ++cb) {
      bp[cb][0] = *(const bf16x8*)&Pl[wv][cb][lc][lh * 8];
      bp[cb][1] = *(const bf16x8*)&Pl[wv][cb][lc][32 + lh * 8];
    }

    __builtin_amdgcn_s_setprio(1);
    #pragma unroll
    for (int nf = 0; nf < 4; ++nf) {
      const int dl = nf * 16 + lc;
      const int c0 = lh ^ (dl & 7), c1 = (4 + lh) ^ (dl & 7);
      bf16x8 av0 = *(const bf16x8*)&Vl[cur][(dl * 8 + c0) * 8];
      bf16x8 av1 = *(const bf16x8*)&Vl[cur][(dl * 8 + c1) * 8];
      #pragma unroll
      for (int cb = 0; cb < 2; ++cb) {
        O[cb][nf] = __builtin_amdgcn_mfma_f32_16x16x32_bf16(av0, bp[cb][0], O[cb][nf], 0, 0, 0);
        O[cb][nf] = __builtin_amdgcn_mfma_f32_16x16x32_bf16(av1, bp[cb][1], O[cb][nf], 0, 0, 0);
      }
    }
    __builtin_amdgcn_s_setprio(0);
  }

  #pragma unroll
  for (int cb = 0; cb < 2; ++cb) {
    const float inv = 1.0f / lr[cb];
    BF16* dst = attout + ((size_t)b * 1024 + i0 + wv * 32 + cb * 16 + lc) * 512 + hh * 64;
    #pragma unroll
    for (int nf = 0; nf < 4; ++nf) {
      ushort4v pk;
      #pragma unroll
      for (int r = 0; r < 4; ++r) pk[r] = f2bf(O[cb][nf][r] * inv);
      *(ushort4v*)&dst[nf * 16 + 4 * lh] = pk;
    }
  }
}

// ---------------------------------------------------------------------------
extern "C" void kernel_launch(void* const* d_in, const int* in_sizes, int n_in,
                              void* d_out, int out_size, void* d_ws, size_t ws_size,
                              hipStream_t stream) {
  const float* x      = (const float*)d_in[0];
  const float* gn_w   = (const float*)d_in[1];
  const float* gn_b   = (const float*)d_in[2];
  const float* qkv_w  = (const float*)d_in[3];
  const float* qkv_b  = (const float*)d_in[4];
  const float* proj_w = (const float*)d_in[5];
  const float* proj_b = (const float*)d_in[6];
  float* out = (float*)d_out;

  char* ws = (char*)d_ws;
  BF16* wq     = (BF16*)(ws);                    // 1.5 MB
  BF16* wp     = (BF16*)(ws + 1572864);          // 0.5 MB
  BF16* h_t    = (BF16*)(ws + 2097152);          // 8 MB
  BF16* q_t    = (BF16*)(ws + 10485760);         // 8 MB
  BF16* k_t    = (BF16*)(ws + 18874368);         // 8 MB
  BF16* v_nat  = (BF16*)(ws + 27262976);         // 8 MB
  float2* stats = (float2*)(ws + 35651584);      // 32 KB; end = 35684352
  BF16* attout = h_t;  // h_t dead after qkv GEMM; reuse for attention output

  stats_cast_kernel<<<1280, 256, 0, stream>>>(x, gn_w, gn_b, qkv_w, proj_w,
                                              stats, wq, wp);
  gn_apply_kernel<<<256, 256, 0, stream>>>(x, stats, h_t);
  qkv_gemm_kernel<<<768, 256, 0, stream>>>(wq, h_t, qkv_b, q_t, k_t, v_nat);
  attn_kernel<<<512, 256, 0, stream>>>(q_t, k_t, v_nat, attout);
  proj_gemm_kernel<<<256, 256, 0, stream>>>(wp, attout, proj_b, x, out);
}